// Round 4
// baseline (223.654 us; speedup 1.0000x reference)
//
#include <hip/hip_runtime.h>
#include <cmath>

// Problem constants (fixed by setup_inputs)
constexpr int NN = 2;       // batch
constexpr int LL = 2048;    // sequence
constexpr int HH = 8;       // heads
constexpr int EE = 32;      // feature dim == value dim
constexpr int CC = 64;      // chunk length
constexpr int NCH = LL / CC;       // 32 chunks per (n,h)
constexpr int NB  = NN * HH * NCH; // 512 blocks
constexpr int BWD = 10;     // softmax bandwidth
constexpr float EPSF = 1e-6f;
// ws record per chunk: S1[32*32], k1[32], S2[32*32], k2[32] (floats)
constexpr int REC  = 2 * (EE * EE + EE);   // 2112 floats = 528 float4
constexpr int REC4 = REC / 4;              // 528
constexpr int OFF_S1 = 0, OFF_K1 = 1024, OFF_S2 = 1056, OFF_K2 = 2080;
constexpr int SK = EE + 4;   // 36: float4-aligned row stride (144 B)
constexpr int SP = EE + 1;   // 33: scalar row stride (bank-staggered)

__device__ __forceinline__ float elu1(float x) {
    return x > 0.f ? x + 1.f : __expf(x);   // elu(x)+1
}

// ---------------- Kernel 1: per-chunk state sums -> ws -----------------------
// one block per (n,h,chunk); 256 threads
__global__ __launch_bounds__(256) void chunksum_kernel(
    const float* __restrict__ Kin, const float* __restrict__ Vin,
    const float* __restrict__ KLin, float* __restrict__ ws)
{
    __shared__ float K1n[CC][SK];
    __shared__ float K2n[CC][SK];
    __shared__ float Vs [CC][SK];

    const int b  = blockIdx.x;
    const int c  = b & (NCH - 1);
    const int nh = b >> 5;
    const int t  = threadIdx.x;
    const int lane = t & 31;
    const int grp  = t >> 5;

    // phase 1: feature map + normalize (half-wave per row)
    for (int r = grp; r < CC; r += 8) {
        const int l = c * CC + r;
        const int base = ((nh >> 3) * LL + l) * HH * EE + (nh & 7) * EE + lane;
        const float k    = Kin[base];
        const float v    = Vin[base];
        const float klen = KLin[(nh >> 3) * LL + l];
        const float f1 = elu1(k);
        const float k1v = f1 * klen;
        const float k2v = f1 * f1 * klen;
        float s1 = k1v, s2 = k2v;
        #pragma unroll
        for (int m = 1; m < 32; m <<= 1) {
            s1 += __shfl_xor(s1, m, 32);
            s2 += __shfl_xor(s2, m, 32);
        }
        K1n[r][lane] = k1v / s1;
        K2n[r][lane] = k2v / s2;
        Vs [r][lane] = v;
    }
    __syncthreads();

    // phase 2: S[e][d] = sum_j K[j][e]*V[j][d]; thread = (e = t>>3, 4 d's)
    // consecutive t -> consecutive d-quad => coalesced float4 ws stores.
    const int e  = t >> 3;
    const int d0 = (t & 7) * 4;
    float4 a1 = {0.f, 0.f, 0.f, 0.f};
    float4 a2 = {0.f, 0.f, 0.f, 0.f};
    float ks1 = 0.f, ks2 = 0.f;
    for (int j = 0; j < CC; ++j) {
        const float k1 = K1n[j][e];     // 8-way broadcast, conflict-free
        const float k2 = K2n[j][e];
        const float4 v = *(const float4*)&Vs[j][d0];
        ks1 += k1; ks2 += k2;
        a1.x += k1 * v.x; a1.y += k1 * v.y; a1.z += k1 * v.z; a1.w += k1 * v.w;
        a2.x += k2 * v.x; a2.y += k2 * v.y; a2.z += k2 * v.z; a2.w += k2 * v.w;
    }
    float* wb = ws + (size_t)b * REC;
    *(float4*)&wb[OFF_S1 + e * EE + d0] = a1;
    *(float4*)&wb[OFF_S2 + e * EE + d0] = a2;
    if ((t & 7) == 0) {
        wb[OFF_K1 + e] = ks1;
        wb[OFF_K2 + e] = ks2;
    }
}

// ---------------- Kernel 2: exclusive prefix over chunks per (n,h) -----------
// grid = NN*HH = 16 blocks, 256 threads  (verbatim from the R1-passing kernel)
__global__ __launch_bounds__(256) void prefix_kernel(float* __restrict__ ws)
{
    const size_t base = (size_t)blockIdx.x * NCH * REC;
    int ids[9]; int cnt = 0;
    for (int i = threadIdx.x; i < REC; i += 256) ids[cnt++] = i;
    float run[9];
    #pragma unroll
    for (int k = 0; k < 9; ++k) run[k] = 0.f;
    for (int cc2 = 0; cc2 < NCH; ++cc2) {
        const size_t cb = base + (size_t)cc2 * REC;
        float v[9];
        for (int k = 0; k < cnt; ++k) v[k] = ws[cb + ids[k]];
        for (int k = 0; k < cnt; ++k) {
            ws[cb + ids[k]] = run[k];
            run[k] += v[k];
        }
    }
}

// ---------------- Kernel 3: band (from LDS) + linear + single store ----------
// one block per (n,h,chunk); 256 threads. Reads ONLY its own ws record b
// (the R1-proven cross-kernel pattern; no multi-record fan-in).
__global__ __launch_bounds__(256) void fused_kernel(
    const float* __restrict__ Qin, const float* __restrict__ Kin,
    const float* __restrict__ Vin, const float* __restrict__ KLin,
    const float* __restrict__ W1, const float* __restrict__ W2,
    const float* __restrict__ W3, const float* __restrict__ ws,
    float* __restrict__ out)
{
    __shared__ float Q1n[CC][SP];          // scalar-read only
    __shared__ float Q2n[CC][SP];
    __shared__ float K1n[CC][SK];          // float4-read rows
    __shared__ float K2n[CC][SK];
    __shared__ float Vs [CC + 9][SK];      // rows l0-9 .. l0+63
    __shared__ float Bnd[CC][SP];          // band partial of out
    // raw-K (band phase) and prefix state (linear phase): disjoint lifetimes
    __shared__ __align__(16) union {
        float kr[(CC + 9) * SP];           // 2409 floats
        float sp[REC];                     // 2112 floats, ws-record layout
    } U;

    const int b  = blockIdx.x;
    const int c  = b & (NCH - 1);
    const int nh = b >> 5;
    const int h  = nh & 7;
    const int n  = nh >> 3;
    const int l0 = c * CC;
    const int t  = threadIdx.x;
    const int lane = t & 31;
    const int grp  = t >> 5;

    // own exclusive-prefix record -> registers early (latency hides under band)
    const float4* wbv = (const float4*)(ws + (size_t)b * REC);
    const float4 s0 = wbv[t];
    const float4 s1 = wbv[t + 256];
    float4 s2 = {0.f, 0.f, 0.f, 0.f};
    if (t < 16) s2 = wbv[t + 512];

    // ---------------- Phase A: load + feature map + normalize ----------------
    float qraw[8];
    {
        int it = 0;
        for (int r = grp; r < CC; r += 8, ++it) {
            const int l = l0 + r;
            const int base = ((n * LL + l) * HH + h) * EE + lane;
            const float q    = Qin[base];
            const float k    = Kin[base];
            const float v    = Vin[base];
            const float klen = KLin[n * LL + l];
            qraw[it] = q;
            const float f1q = elu1(q);
            const float f1k = elu1(k);
            const float q2v = f1q * f1q;
            const float k1v = f1k * klen;
            const float k2v = f1k * f1k * klen;
            float sq1 = f1q, sq2 = q2v, sk1 = k1v, sk2 = k2v;
            #pragma unroll
            for (int m = 1; m < 32; m <<= 1) {
                sq1 += __shfl_xor(sq1, m, 32);
                sq2 += __shfl_xor(sq2, m, 32);
                sk1 += __shfl_xor(sk1, m, 32);
                sk2 += __shfl_xor(sk2, m, 32);
            }
            Q1n[r][lane] = f1q / sq1;
            Q2n[r][lane] = q2v / sq2;
            K1n[r][lane] = k1v / sk1;
            K2n[r][lane] = k2v / sk2;
            Vs [9 + r][lane] = v;
            U.kr[(9 + r) * SP + lane] = k;
        }
    }
    // previous 9 rows of raw K,V for the band window
    for (int idx = t; idx < 9 * 32; idx += 256) {
        const int rr = idx >> 5, ln = idx & 31;
        const int l = l0 - 9 + rr;
        float kv = 0.f, vv = 0.f;
        if (l >= 0) {
            const int base = ((n * LL + l) * HH + h) * EE + ln;
            kv = Kin[base];
            vv = Vin[base];
        }
        U.kr[rr * SP + ln] = kv;
        Vs[rr][ln] = vv;
    }
    __syncthreads();

    // ---------------- Phase B: banded softmax from LDS -----------------------
    {
        const float temp = 0.17677669529663687f;   // 1/sqrt(32)
        const float w1v = W1[h * EE + lane];
        int it = 0;
        for (int r = grp; r < CC; r += 8, ++it) {
            const int l = l0 + r;
            const float q = qraw[it];
            float sarr[BWD];
            #pragma unroll
            for (int jj = 0; jj < BWD; ++jj) {
                const int j = l - (BWD - 1) + jj;
                float s = -INFINITY;
                if (j >= 0) {
                    float p = q * U.kr[(r + jj) * SP + lane];
                    #pragma unroll
                    for (int m = 1; m < 32; m <<= 1) p += __shfl_xor(p, m, 32);
                    s = p * temp;
                }
                sarr[jj] = s;
            }
            float mx = -INFINITY;
            #pragma unroll
            for (int jj = 0; jj < BWD; ++jj) mx = fmaxf(mx, sarr[jj]);
            float sum = 0.f;
            #pragma unroll
            for (int jj = 0; jj < BWD; ++jj) {
                const int j = l - (BWD - 1) + jj;
                float p = (j >= 0) ? __expf(sarr[jj] - mx) : 0.f;
                sarr[jj] = p;
                sum += p;
            }
            const float inv = 1.f / sum;
            float sv = 0.f;
            #pragma unroll
            for (int jj = 0; jj < BWD; ++jj) sv += sarr[jj] * Vs[r + jj][lane];
            Bnd[r][lane] = w1v * (sv * inv);
        }
    }
    __syncthreads();   // all reads of U.kr done

    // publish own prefix record into U.sp (same layout as ws record)
    ((float4*)U.sp)[t]       = s0;
    ((float4*)U.sp)[t + 256] = s1;
    if (t < 16) ((float4*)U.sp)[t + 512] = s2;
    __syncthreads();

    const float* S1p = U.sp + OFF_S1;
    const float* S2p = U.sp + OFF_S2;
    const float* k1p = U.sp + OFF_K1;
    const float* k2p = U.sp + OFF_K2;

    // ---------------- Phase C: chunked causal linear + epilogue --------------
    // 4 threads per row; sub handles d in [sub*8, sub*8+8)
    const int r   = t >> 2;
    const int sub = t & 3;
    const int d0  = sub * 8;

    float acc1[8], acc2[8];
    #pragma unroll
    for (int dd = 0; dd < 8; ++dd) { acc1[dd] = 0.f; acc2[dd] = 0.f; }
    float den1 = 0.f, den2 = 0.f;

    // prefix contribution: Qn_r @ S_pre, Qn_r . k_pre (float4 state reads)
    for (int e = 0; e < EE; ++e) {
        const float q1 = Q1n[r][e];
        const float q2 = Q2n[r][e];
        den1 += q1 * k1p[e];
        den2 += q2 * k2p[e];
        const float4 sa = *(const float4*)&S1p[e * EE + d0];
        const float4 sb = *(const float4*)&S1p[e * EE + d0 + 4];
        const float4 ta = *(const float4*)&S2p[e * EE + d0];
        const float4 tb = *(const float4*)&S2p[e * EE + d0 + 4];
        acc1[0] += q1 * sa.x; acc1[1] += q1 * sa.y; acc1[2] += q1 * sa.z; acc1[3] += q1 * sa.w;
        acc1[4] += q1 * sb.x; acc1[5] += q1 * sb.y; acc1[6] += q1 * sb.z; acc1[7] += q1 * sb.w;
        acc2[0] += q2 * ta.x; acc2[1] += q2 * ta.y; acc2[2] += q2 * ta.z; acc2[3] += q2 * ta.w;
        acc2[4] += q2 * tb.x; acc2[5] += q2 * tb.y; acc2[6] += q2 * tb.z; acc2[7] += q2 * tb.w;
    }

    float q1r[8], q2r[8];
    #pragma unroll
    for (int i = 0; i < 8; ++i) {
        q1r[i] = Q1n[r][d0 + i];
        q2r[i] = Q2n[r][d0 + i];
    }

    for (int j = 0; j <= r; ++j) {
        const float4 ka = *(const float4*)&K1n[j][d0];
        const float4 kb = *(const float4*)&K1n[j][d0 + 4];
        const float4 la = *(const float4*)&K2n[j][d0];
        const float4 lb = *(const float4*)&K2n[j][d0 + 4];
        float p1 = q1r[0]*ka.x + q1r[1]*ka.y + q1r[2]*ka.z + q1r[3]*ka.w
                 + q1r[4]*kb.x + q1r[5]*kb.y + q1r[6]*kb.z + q1r[7]*kb.w;
        float p2 = q2r[0]*la.x + q2r[1]*la.y + q2r[2]*la.z + q2r[3]*la.w
                 + q2r[4]*lb.x + q2r[5]*lb.y + q2r[6]*lb.z + q2r[7]*lb.w;
        p1 += __shfl_xor(p1, 1, 4); p1 += __shfl_xor(p1, 2, 4);
        p2 += __shfl_xor(p2, 1, 4); p2 += __shfl_xor(p2, 2, 4);
        den1 += p1;
        den2 += p2;
        const float4 va = *(const float4*)&Vs[9 + j][d0];
        const float4 vb = *(const float4*)&Vs[9 + j][d0 + 4];
        acc1[0] += p1 * va.x; acc1[1] += p1 * va.y; acc1[2] += p1 * va.z; acc1[3] += p1 * va.w;
        acc1[4] += p1 * vb.x; acc1[5] += p1 * vb.y; acc1[6] += p1 * vb.z; acc1[7] += p1 * vb.w;
        acc2[0] += p2 * va.x; acc2[1] += p2 * va.y; acc2[2] += p2 * va.z; acc2[3] += p2 * va.w;
        acc2[4] += p2 * vb.x; acc2[5] += p2 * vb.y; acc2[6] += p2 * vb.z; acc2[7] += p2 * vb.w;
    }

    const float z1 = 1.f / (den1 + EPSF);
    const float z2 = 1.f / (den2 + EPSF);
    const int l = l0 + r;
    const int ob = ((n * LL + l) * HH + h) * EE + d0;
    float4 o0, o1;
    {
        float tmp[8];
        #pragma unroll
        for (int dd = 0; dd < 8; ++dd) {
            const int d = d0 + dd;
            tmp[dd] = Bnd[r][d]
                    + W2[h * EE + d] * acc1[dd] * z1
                    + W3[h * EE + d] * acc2[dd] * z2;
        }
        o0.x = tmp[0]; o0.y = tmp[1]; o0.z = tmp[2]; o0.w = tmp[3];
        o1.x = tmp[4]; o1.y = tmp[5]; o1.z = tmp[6]; o1.w = tmp[7];
    }
    *(float4*)&out[ob]     = o0;
    *(float4*)&out[ob + 4] = o1;
}

extern "C" void kernel_launch(void* const* d_in, const int* in_sizes, int n_in,
                              void* d_out, int out_size, void* d_ws, size_t ws_size,
                              hipStream_t stream)
{
    const float* Q  = (const float*)d_in[0];
    const float* K  = (const float*)d_in[1];
    const float* V  = (const float*)d_in[2];
    const float* KL = (const float*)d_in[3];
    const float* W1 = (const float*)d_in[4];
    const float* W2 = (const float*)d_in[5];
    const float* W3 = (const float*)d_in[6];
    float* out = (float*)d_out;
    float* ws  = (float*)d_ws;   // uses NB*REC*4 = ~4.3 MB of scratch

    chunksum_kernel<<<NB,      256, 0, stream>>>(K, V, KL, ws);
    prefix_kernel  <<<NN * HH, 256, 0, stream>>>(ws);
    fused_kernel   <<<NB,      256, 0, stream>>>(Q, K, V, KL, W1, W2, W3, ws, out);
}

// Round 5
// 127.715 us; speedup vs baseline: 1.7512x; 1.7512x over previous
//
#include <hip/hip_runtime.h>
#include <cmath>

// Problem constants (fixed by setup_inputs)
constexpr int NN = 2;       // batch
constexpr int LL = 2048;    // sequence
constexpr int HH = 8;       // heads
constexpr int EE = 32;      // feature dim == value dim
constexpr int CC = 64;      // chunk length
constexpr int NCH = LL / CC;       // 32 chunks per (n,h)
constexpr int NB  = NN * HH * NCH; // 512 blocks
constexpr int BWD = 10;     // softmax bandwidth
constexpr float EPSF = 1e-6f;
// ws record per chunk: S1[32*32], k1[32], S2[32*32], k2[32] (floats)
constexpr int REC  = 2 * (EE * EE + EE);   // 2112 floats = 528 float4
constexpr int REC4 = REC / 4;              // 528
constexpr int OFF_S1 = 0, OFF_K1 = 1024, OFF_S2 = 1056, OFF_K2 = 2080;
constexpr int SK = EE + 4;   // 36: float4-aligned row stride (144 B)
constexpr int SP = EE + 1;   // 33: scalar row stride (bank-staggered)

__device__ __forceinline__ float elu1(float x) {
    return x > 0.f ? x + 1.f : __expf(x);   // elu(x)+1
}

// ---------------- Kernel 1: per-chunk state sums -> ws -----------------------
// one block per (n,h,chunk); 256 threads
__global__ __launch_bounds__(256) void chunksum_kernel(
    const float* __restrict__ Kin, const float* __restrict__ Vin,
    const float* __restrict__ KLin, float* __restrict__ ws)
{
    __shared__ float K1n[CC][SK];
    __shared__ float K2n[CC][SK];
    __shared__ float Vs [CC][SK];

    const int b  = blockIdx.x;
    const int c  = b & (NCH - 1);
    const int nh = b >> 5;
    const int t  = threadIdx.x;
    const int lane = t & 31;
    const int grp  = t >> 5;

    // phase 1: feature map + normalize (half-wave per row)
    for (int r = grp; r < CC; r += 8) {
        const int l = c * CC + r;
        const int base = ((nh >> 3) * LL + l) * HH * EE + (nh & 7) * EE + lane;
        const float k    = Kin[base];
        const float v    = Vin[base];
        const float klen = KLin[(nh >> 3) * LL + l];
        const float f1 = elu1(k);
        const float k1v = f1 * klen;
        const float k2v = f1 * f1 * klen;
        float s1 = k1v, s2 = k2v;
        #pragma unroll
        for (int m = 1; m < 32; m <<= 1) {
            s1 += __shfl_xor(s1, m, 32);
            s2 += __shfl_xor(s2, m, 32);
        }
        K1n[r][lane] = k1v / s1;
        K2n[r][lane] = k2v / s2;
        Vs [r][lane] = v;
    }
    __syncthreads();

    // phase 2: S[e][d] = sum_j K[j][e]*V[j][d]; thread = (e = t>>3, 4 d's)
    // consecutive t -> consecutive d-quad => coalesced float4 ws stores.
    const int e  = t >> 3;
    const int d0 = (t & 7) * 4;
    float4 a1 = {0.f, 0.f, 0.f, 0.f};
    float4 a2 = {0.f, 0.f, 0.f, 0.f};
    float ks1 = 0.f, ks2 = 0.f;
    for (int j = 0; j < CC; ++j) {
        const float k1 = K1n[j][e];     // 8-way broadcast, conflict-free
        const float k2 = K2n[j][e];
        const float4 v = *(const float4*)&Vs[j][d0];
        ks1 += k1; ks2 += k2;
        a1.x += k1 * v.x; a1.y += k1 * v.y; a1.z += k1 * v.z; a1.w += k1 * v.w;
        a2.x += k2 * v.x; a2.y += k2 * v.y; a2.z += k2 * v.z; a2.w += k2 * v.w;
    }
    float* wb = ws + (size_t)b * REC;
    *(float4*)&wb[OFF_S1 + e * EE + d0] = a1;
    *(float4*)&wb[OFF_S2 + e * EE + d0] = a2;
    if ((t & 7) == 0) {
        wb[OFF_K1 + e] = ks1;
        wb[OFF_K2 + e] = ks2;
    }
}

// ---------------- Kernel 2: exclusive prefix over chunks per (n,h) -----------
// REGISTER SCAN: thread owns one (group, entry) column. 32 independent
// coalesced loads (pipelined, L2-hot) -> 31 register adds -> 32 coalesced
// stores. Replaces the 16-block serial version that ran 100 us at 0.6%
// occupancy (R4 rocprof). Same per-entry summation order => identical bits.
// grid = 16 groups x 11 blocks of 192 threads (192*11 == REC exactly)
__global__ __launch_bounds__(192) void prefix_kernel(float* __restrict__ ws)
{
    const int g = blockIdx.x / 11;
    const int e = (blockIdx.x % 11) * 192 + threadIdx.x;   // 0..2111
    float* base = ws + (size_t)g * NCH * REC + e;
    float v[NCH];
    #pragma unroll
    for (int c = 0; c < NCH; ++c) v[c] = base[(size_t)c * REC];
    float run = 0.f;
    #pragma unroll
    for (int c = 0; c < NCH; ++c) {
        const float x = v[c];
        base[(size_t)c * REC] = run;
        run += x;
    }
}

// ---------------- Kernel 3: band (from LDS) + linear + single store ----------
// one block per (n,h,chunk); 256 threads. Reads ONLY its own ws record b
// (the R1/R4-proven cross-kernel pattern; no multi-record fan-in).
__global__ __launch_bounds__(256) void fused_kernel(
    const float* __restrict__ Qin, const float* __restrict__ Kin,
    const float* __restrict__ Vin, const float* __restrict__ KLin,
    const float* __restrict__ W1, const float* __restrict__ W2,
    const float* __restrict__ W3, const float* __restrict__ ws,
    float* __restrict__ out)
{
    __shared__ float Q1n[CC][SP];          // scalar-read only
    __shared__ float Q2n[CC][SP];
    __shared__ float K1n[CC][SK];          // float4-read rows
    __shared__ float K2n[CC][SK];
    __shared__ float Vs [CC + 9][SK];      // rows l0-9 .. l0+63
    __shared__ float Bnd[CC][SP];          // band partial of out
    // raw-K (band phase) and prefix state (linear phase): disjoint lifetimes
    __shared__ __align__(16) union {
        float kr[(CC + 9) * SP];           // 2409 floats
        float sp[REC];                     // 2112 floats, ws-record layout
    } U;

    const int b  = blockIdx.x;
    const int c  = b & (NCH - 1);
    const int nh = b >> 5;
    const int h  = nh & 7;
    const int n  = nh >> 3;
    const int l0 = c * CC;
    const int t  = threadIdx.x;
    const int lane = t & 31;
    const int grp  = t >> 5;

    // own exclusive-prefix record -> registers early (latency hides under band)
    const float4* wbv = (const float4*)(ws + (size_t)b * REC);
    const float4 s0 = wbv[t];
    const float4 s1 = wbv[t + 256];
    float4 s2 = {0.f, 0.f, 0.f, 0.f};
    if (t < 16) s2 = wbv[t + 512];

    // ---------------- Phase A: load + feature map + normalize ----------------
    float qraw[8];
    {
        int it = 0;
        for (int r = grp; r < CC; r += 8, ++it) {
            const int l = l0 + r;
            const int base = ((n * LL + l) * HH + h) * EE + lane;
            const float q    = Qin[base];
            const float k    = Kin[base];
            const float v    = Vin[base];
            const float klen = KLin[n * LL + l];
            qraw[it] = q;
            const float f1q = elu1(q);
            const float f1k = elu1(k);
            const float q2v = f1q * f1q;
            const float k1v = f1k * klen;
            const float k2v = f1k * f1k * klen;
            float sq1 = f1q, sq2 = q2v, sk1 = k1v, sk2 = k2v;
            #pragma unroll
            for (int m = 1; m < 32; m <<= 1) {
                sq1 += __shfl_xor(sq1, m, 32);
                sq2 += __shfl_xor(sq2, m, 32);
                sk1 += __shfl_xor(sk1, m, 32);
                sk2 += __shfl_xor(sk2, m, 32);
            }
            Q1n[r][lane] = f1q / sq1;
            Q2n[r][lane] = q2v / sq2;
            K1n[r][lane] = k1v / sk1;
            K2n[r][lane] = k2v / sk2;
            Vs [9 + r][lane] = v;
            U.kr[(9 + r) * SP + lane] = k;
        }
    }
    // previous 9 rows of raw K,V for the band window
    for (int idx = t; idx < 9 * 32; idx += 256) {
        const int rr = idx >> 5, ln = idx & 31;
        const int l = l0 - 9 + rr;
        float kv = 0.f, vv = 0.f;
        if (l >= 0) {
            const int base = ((n * LL + l) * HH + h) * EE + ln;
            kv = Kin[base];
            vv = Vin[base];
        }
        U.kr[rr * SP + ln] = kv;
        Vs[rr][ln] = vv;
    }
    __syncthreads();

    // ---------------- Phase B: banded softmax from LDS -----------------------
    {
        const float temp = 0.17677669529663687f;   // 1/sqrt(32)
        const float w1v = W1[h * EE + lane];
        int it = 0;
        for (int r = grp; r < CC; r += 8, ++it) {
            const int l = l0 + r;
            const float q = qraw[it];
            float sarr[BWD];
            #pragma unroll
            for (int jj = 0; jj < BWD; ++jj) {
                const int j = l - (BWD - 1) + jj;
                float s = -INFINITY;
                if (j >= 0) {
                    float p = q * U.kr[(r + jj) * SP + lane];
                    #pragma unroll
                    for (int m = 1; m < 32; m <<= 1) p += __shfl_xor(p, m, 32);
                    s = p * temp;
                }
                sarr[jj] = s;
            }
            float mx = -INFINITY;
            #pragma unroll
            for (int jj = 0; jj < BWD; ++jj) mx = fmaxf(mx, sarr[jj]);
            float sum = 0.f;
            #pragma unroll
            for (int jj = 0; jj < BWD; ++jj) {
                const int j = l - (BWD - 1) + jj;
                float p = (j >= 0) ? __expf(sarr[jj] - mx) : 0.f;
                sarr[jj] = p;
                sum += p;
            }
            const float inv = 1.f / sum;
            float sv = 0.f;
            #pragma unroll
            for (int jj = 0; jj < BWD; ++jj) sv += sarr[jj] * Vs[r + jj][lane];
            Bnd[r][lane] = w1v * (sv * inv);
        }
    }
    __syncthreads();   // all reads of U.kr done

    // publish own prefix record into U.sp (same layout as ws record)
    ((float4*)U.sp)[t]       = s0;
    ((float4*)U.sp)[t + 256] = s1;
    if (t < 16) ((float4*)U.sp)[t + 512] = s2;
    __syncthreads();

    const float* S1p = U.sp + OFF_S1;
    const float* S2p = U.sp + OFF_S2;
    const float* k1p = U.sp + OFF_K1;
    const float* k2p = U.sp + OFF_K2;

    // ---------------- Phase C: chunked causal linear + epilogue --------------
    // 4 threads per row; sub handles d in [sub*8, sub*8+8)
    const int r   = t >> 2;
    const int sub = t & 3;
    const int d0  = sub * 8;

    float acc1[8], acc2[8];
    #pragma unroll
    for (int dd = 0; dd < 8; ++dd) { acc1[dd] = 0.f; acc2[dd] = 0.f; }
    float den1 = 0.f, den2 = 0.f;

    // prefix contribution: Qn_r @ S_pre, Qn_r . k_pre (float4 state reads)
    for (int e = 0; e < EE; ++e) {
        const float q1 = Q1n[r][e];
        const float q2 = Q2n[r][e];
        den1 += q1 * k1p[e];
        den2 += q2 * k2p[e];
        const float4 sa = *(const float4*)&S1p[e * EE + d0];
        const float4 sb = *(const float4*)&S1p[e * EE + d0 + 4];
        const float4 ta = *(const float4*)&S2p[e * EE + d0];
        const float4 tb = *(const float4*)&S2p[e * EE + d0 + 4];
        acc1[0] += q1 * sa.x; acc1[1] += q1 * sa.y; acc1[2] += q1 * sa.z; acc1[3] += q1 * sa.w;
        acc1[4] += q1 * sb.x; acc1[5] += q1 * sb.y; acc1[6] += q1 * sb.z; acc1[7] += q1 * sb.w;
        acc2[0] += q2 * ta.x; acc2[1] += q2 * ta.y; acc2[2] += q2 * ta.z; acc2[3] += q2 * ta.w;
        acc2[4] += q2 * tb.x; acc2[5] += q2 * tb.y; acc2[6] += q2 * tb.z; acc2[7] += q2 * tb.w;
    }

    float q1r[8], q2r[8];
    #pragma unroll
    for (int i = 0; i < 8; ++i) {
        q1r[i] = Q1n[r][d0 + i];
        q2r[i] = Q2n[r][d0 + i];
    }

    for (int j = 0; j <= r; ++j) {
        const float4 ka = *(const float4*)&K1n[j][d0];
        const float4 kb = *(const float4*)&K1n[j][d0 + 4];
        const float4 la = *(const float4*)&K2n[j][d0];
        const float4 lb = *(const float4*)&K2n[j][d0 + 4];
        float p1 = q1r[0]*ka.x + q1r[1]*ka.y + q1r[2]*ka.z + q1r[3]*ka.w
                 + q1r[4]*kb.x + q1r[5]*kb.y + q1r[6]*kb.z + q1r[7]*kb.w;
        float p2 = q2r[0]*la.x + q2r[1]*la.y + q2r[2]*la.z + q2r[3]*la.w
                 + q2r[4]*lb.x + q2r[5]*lb.y + q2r[6]*lb.z + q2r[7]*lb.w;
        p1 += __shfl_xor(p1, 1, 4); p1 += __shfl_xor(p1, 2, 4);
        p2 += __shfl_xor(p2, 1, 4); p2 += __shfl_xor(p2, 2, 4);
        den1 += p1;
        den2 += p2;
        const float4 va = *(const float4*)&Vs[9 + j][d0];
        const float4 vb = *(const float4*)&Vs[9 + j][d0 + 4];
        acc1[0] += p1 * va.x; acc1[1] += p1 * va.y; acc1[2] += p1 * va.z; acc1[3] += p1 * va.w;
        acc1[4] += p1 * vb.x; acc1[5] += p1 * vb.y; acc1[6] += p1 * vb.z; acc1[7] += p1 * vb.w;
        acc2[0] += p2 * va.x; acc2[1] += p2 * va.y; acc2[2] += p2 * va.z; acc2[3] += p2 * va.w;
        acc2[4] += p2 * vb.x; acc2[5] += p2 * vb.y; acc2[6] += p2 * vb.z; acc2[7] += p2 * vb.w;
    }

    const float z1 = 1.f / (den1 + EPSF);
    const float z2 = 1.f / (den2 + EPSF);
    const int l = l0 + r;
    const int ob = ((n * LL + l) * HH + h) * EE + d0;
    float4 o0, o1;
    {
        float tmp[8];
        #pragma unroll
        for (int dd = 0; dd < 8; ++dd) {
            const int d = d0 + dd;
            tmp[dd] = Bnd[r][d]
                    + W2[h * EE + d] * acc1[dd] * z1
                    + W3[h * EE + d] * acc2[dd] * z2;
        }
        o0.x = tmp[0]; o0.y = tmp[1]; o0.z = tmp[2]; o0.w = tmp[3];
        o1.x = tmp[4]; o1.y = tmp[5]; o1.z = tmp[6]; o1.w = tmp[7];
    }
    *(float4*)&out[ob]     = o0;
    *(float4*)&out[ob + 4] = o1;
}

extern "C" void kernel_launch(void* const* d_in, const int* in_sizes, int n_in,
                              void* d_out, int out_size, void* d_ws, size_t ws_size,
                              hipStream_t stream)
{
    const float* Q  = (const float*)d_in[0];
    const float* K  = (const float*)d_in[1];
    const float* V  = (const float*)d_in[2];
    const float* KL = (const float*)d_in[3];
    const float* W1 = (const float*)d_in[4];
    const float* W2 = (const float*)d_in[5];
    const float* W3 = (const float*)d_in[6];
    float* out = (float*)d_out;
    float* ws  = (float*)d_ws;   // uses NB*REC*4 = ~4.3 MB of scratch

    chunksum_kernel<<<NB,          256, 0, stream>>>(K, V, KL, ws);
    prefix_kernel  <<<NN * HH * 11, 192, 0, stream>>>(ws);
    fused_kernel   <<<NB,          256, 0, stream>>>(Q, K, V, KL, W1, W2, W3, ws, out);
}

// Round 6
// 117.453 us; speedup vs baseline: 1.9042x; 1.0874x over previous
//
#include <hip/hip_runtime.h>
#include <cmath>

// Problem constants (fixed by setup_inputs)
constexpr int NN = 2;       // batch
constexpr int LL = 2048;    // sequence
constexpr int HH = 8;       // heads
constexpr int EE = 32;      // feature dim == value dim
constexpr int CC = 64;      // chunk length
constexpr int NCH = LL / CC;       // 32 chunks per (n,h)
constexpr int NB  = NN * HH * NCH; // 512 blocks
constexpr int BWD = 10;     // softmax bandwidth
constexpr float EPSF = 1e-6f;
// ws record per chunk: S1[32*32], k1[32], S2[32*32], k2[32] (floats)
constexpr int REC  = 2 * (EE * EE + EE);   // 2112 floats = 528 float4
constexpr int REC4 = REC / 4;              // 528
constexpr int OFF_S1 = 0, OFF_K1 = 1024, OFF_S2 = 1056, OFF_K2 = 2080;
constexpr int SK = EE + 4;   // 36: float4-aligned row stride (144 B)

__device__ __forceinline__ float elu1(float x) {
    return x > 0.f ? x + 1.f : __expf(x);   // elu(x)+1
}

// ---------------- Kernel 1: per-chunk state sums -> ws -----------------------
// one block per (n,h,chunk); 512 threads (R5 had 256 -> 2 waves/SIMD only)
__global__ __launch_bounds__(512) void chunksum_kernel(
    const float* __restrict__ Kin, const float* __restrict__ Vin,
    const float* __restrict__ KLin, float* __restrict__ ws)
{
    __shared__ float K1n[CC][SK];
    __shared__ float K2n[CC][SK];
    __shared__ float Vs [CC][SK];

    const int b  = blockIdx.x;
    const int c  = b & (NCH - 1);
    const int nh = b >> 5;
    const int t  = threadIdx.x;
    const int lane = t & 31;
    const int grp  = t >> 5;    // 0..15

    // phase 1: feature map + normalize (half-wave per row, 4 rows each)
    for (int r = grp; r < CC; r += 16) {
        const int l = c * CC + r;
        const int base = ((nh >> 3) * LL + l) * HH * EE + (nh & 7) * EE + lane;
        const float k    = Kin[base];
        const float v    = Vin[base];
        const float klen = KLin[(nh >> 3) * LL + l];
        const float f1 = elu1(k);
        const float k1v = f1 * klen;
        const float k2v = f1 * f1 * klen;
        float s1 = k1v, s2 = k2v;
        #pragma unroll
        for (int m = 1; m < 32; m <<= 1) {
            s1 += __shfl_xor(s1, m, 32);
            s2 += __shfl_xor(s2, m, 32);
        }
        K1n[r][lane] = k1v / s1;
        K2n[r][lane] = k2v / s2;
        Vs [r][lane] = v;
    }
    __syncthreads();

    // phase 2: S[e][d] = sum_j K[j][e]*V[j][d]; thread = (e = t>>4, 2 d's)
    // same ascending-j order as R5 => bit-identical ws entries.
    const int e  = t >> 4;          // 0..31
    const int d0 = (t & 15) * 2;    // 0..30
    float a1x = 0.f, a1y = 0.f, a2x = 0.f, a2y = 0.f;
    float ks1 = 0.f, ks2 = 0.f;
    for (int j = 0; j < CC; ++j) {
        const float k1 = K1n[j][e];     // 16-way same-address broadcast
        const float k2 = K2n[j][e];
        const float2 v = *(const float2*)&Vs[j][d0];
        ks1 += k1; ks2 += k2;
        a1x += k1 * v.x; a1y += k1 * v.y;
        a2x += k2 * v.x; a2y += k2 * v.y;
    }
    float* wb = ws + (size_t)b * REC;
    *(float2*)&wb[OFF_S1 + e * EE + d0] = make_float2(a1x, a1y);
    *(float2*)&wb[OFF_S2 + e * EE + d0] = make_float2(a2x, a2y);
    if ((t & 15) == 0) {
        wb[OFF_K1 + e] = ks1;
        wb[OFF_K2 + e] = ks2;
    }
}

// ---------------- Kernel 2: exclusive prefix over chunks per (n,h) -----------
// register scan, proven in R5 (100us -> off the profile)
// grid = 16 groups x 11 blocks of 192 threads (192*11 == REC exactly)
__global__ __launch_bounds__(192) void prefix_kernel(float* __restrict__ ws)
{
    const int g = blockIdx.x / 11;
    const int e = (blockIdx.x % 11) * 192 + threadIdx.x;   // 0..2111
    float* base = ws + (size_t)g * NCH * REC + e;
    float v[NCH];
    #pragma unroll
    for (int c = 0; c < NCH; ++c) v[c] = base[(size_t)c * REC];
    float run = 0.f;
    #pragma unroll
    for (int c = 0; c < NCH; ++c) {
        const float x = v[c];
        base[(size_t)c * REC] = run;
        run += x;
    }
}

// ---------------- Kernel 3: band + linear + single store ---------------------
// one block per (n,h,chunk); 512 threads = 8-lane cluster per row, 4 features
// per lane. Q never touches LDS (registers + width-8 shuffles). LDS 39.5 KB
// (R5: 64 KB). Reads ONLY its own ws record b (proven dataflow).
__global__ __launch_bounds__(512, 4) void fused_kernel(
    const float* __restrict__ Qin, const float* __restrict__ Kin,
    const float* __restrict__ Vin, const float* __restrict__ KLin,
    const float* __restrict__ W1, const float* __restrict__ W2,
    const float* __restrict__ W3, const float* __restrict__ ws,
    float* __restrict__ out)
{
    __shared__ float K1n[CC][SK];          // normalized K, float4-read rows
    __shared__ float K2n[CC][SK];
    __shared__ float Vs [CC + 9][SK];      // rows l0-9 .. l0+63
    // raw-K (band phase) and prefix state (linear phase): disjoint lifetimes
    __shared__ __align__(16) union {
        float kr[(CC + 9) * SK];           // 2628 floats
        float sp[REC];                     // 2112 floats, ws-record layout
    } U;

    const int b  = blockIdx.x;
    const int c  = b & (NCH - 1);
    const int nh = b >> 5;
    const int h  = nh & 7;
    const int n  = nh >> 3;
    const int l0 = c * CC;
    const int t  = threadIdx.x;
    const int lane = t & 31;
    const int grp  = t >> 5;

    // own exclusive-prefix record -> registers early (latency hides under A/B)
    const float4* wbv = (const float4*)(ws + (size_t)b * REC);
    const float4 s0 = wbv[t];                       // 512 of 528
    float4 s1 = {0.f, 0.f, 0.f, 0.f};
    if (t < REC4 - 512) s1 = wbv[512 + t];          // last 16

    // ---------------- Phase A: K/V staging + feature map + normalize ---------
    for (int r = grp; r < CC; r += 16) {
        const int l = l0 + r;
        const int base = ((n * LL + l) * HH + h) * EE + lane;
        const float k    = Kin[base];
        const float v    = Vin[base];
        const float klen = KLin[n * LL + l];
        const float f1 = elu1(k);
        const float k1v = f1 * klen;
        const float k2v = f1 * f1 * klen;
        float sk1 = k1v, sk2 = k2v;
        #pragma unroll
        for (int m = 1; m < 32; m <<= 1) {
            sk1 += __shfl_xor(sk1, m, 32);
            sk2 += __shfl_xor(sk2, m, 32);
        }
        K1n[r][lane] = k1v / sk1;
        K2n[r][lane] = k2v / sk2;
        Vs [9 + r][lane] = v;
        U.kr[(9 + r) * SK + lane] = k;
    }
    // previous 9 rows of raw K,V for the band window (288 threads, 1 iter)
    if (t < 9 * 32) {
        const int rr = t >> 5, ln = t & 31;
        const int l = l0 - 9 + rr;
        float kv = 0.f, vv = 0.f;
        if (l >= 0) {
            const int base = ((n * LL + l) * HH + h) * EE + ln;
            kv = Kin[base];
            vv = Vin[base];
        }
        U.kr[rr * SK + ln] = kv;
        Vs[rr][ln] = vv;
    }

    // ---------------- Q in cluster layout: registers only --------------------
    const int r   = t >> 3;        // row 0..63
    const int sub = t & 7;
    const int d0  = sub * 4;
    const int l   = l0 + r;
    const float4 q4 = *(const float4*)&Qin[((n * LL + l) * HH + h) * EE + d0];
    float q1r[4], q2r[4];
    {
        float f0 = elu1(q4.x), f1 = elu1(q4.y), f2 = elu1(q4.z), f3 = elu1(q4.w);
        float sq1 = f0 + f1 + f2 + f3;
        float sq2 = f0*f0 + f1*f1 + f2*f2 + f3*f3;
        sq1 += __shfl_xor(sq1, 1, 8); sq1 += __shfl_xor(sq1, 2, 8); sq1 += __shfl_xor(sq1, 4, 8);
        sq2 += __shfl_xor(sq2, 1, 8); sq2 += __shfl_xor(sq2, 2, 8); sq2 += __shfl_xor(sq2, 4, 8);
        const float i1 = 1.f / sq1, i2 = 1.f / sq2;
        q1r[0] = f0 * i1; q1r[1] = f1 * i1; q1r[2] = f2 * i1; q1r[3] = f3 * i1;
        q2r[0] = f0*f0 * i2; q2r[1] = f1*f1 * i2; q2r[2] = f2*f2 * i2; q2r[3] = f3*f3 * i2;
    }
    __syncthreads();

    // ---------------- Phase B: banded softmax, cluster dots, regs out --------
    float bnd[4];
    {
        const float temp = 0.17677669529663687f;   // 1/sqrt(32)
        float sarr[BWD];
        #pragma unroll
        for (int jj = 0; jj < BWD; ++jj) {
            const int j = l - (BWD - 1) + jj;
            float s = -INFINITY;
            if (j >= 0) {
                const float4 k4 = *(const float4*)&U.kr[(r + jj) * SK + d0];
                float p = q4.x*k4.x + q4.y*k4.y + q4.z*k4.z + q4.w*k4.w;
                p += __shfl_xor(p, 1, 8); p += __shfl_xor(p, 2, 8); p += __shfl_xor(p, 4, 8);
                s = p * temp;
            }
            sarr[jj] = s;
        }
        float mx = -INFINITY;
        #pragma unroll
        for (int jj = 0; jj < BWD; ++jj) mx = fmaxf(mx, sarr[jj]);
        float sum = 0.f;
        #pragma unroll
        for (int jj = 0; jj < BWD; ++jj) {
            const int j = l - (BWD - 1) + jj;
            const float p = (j >= 0) ? __expf(sarr[jj] - mx) : 0.f;
            sarr[jj] = p;
            sum += p;
        }
        const float inv = 1.f / sum;
        float sv0 = 0.f, sv1 = 0.f, sv2 = 0.f, sv3 = 0.f;
        #pragma unroll
        for (int jj = 0; jj < BWD; ++jj) {
            const float4 v4 = *(const float4*)&Vs[r + jj][d0];   // sarr==0 if masked
            sv0 += sarr[jj] * v4.x; sv1 += sarr[jj] * v4.y;
            sv2 += sarr[jj] * v4.z; sv3 += sarr[jj] * v4.w;
        }
        const float4 w1 = *(const float4*)&W1[h * EE + d0];
        bnd[0] = w1.x * sv0 * inv; bnd[1] = w1.y * sv1 * inv;
        bnd[2] = w1.z * sv2 * inv; bnd[3] = w1.w * sv3 * inv;
    }
    __syncthreads();   // all reads of U.kr done

    // publish own prefix record into U.sp (same layout as ws record)
    ((float4*)U.sp)[t] = s0;
    if (t < REC4 - 512) ((float4*)U.sp)[512 + t] = s1;
    __syncthreads();

    const float* S1p = U.sp + OFF_S1;
    const float* S2p = U.sp + OFF_S2;
    const float* k1p = U.sp + OFF_K1;
    const float* k2p = U.sp + OFF_K2;

    // ---------------- Phase C: chunked causal linear + epilogue --------------
    float acc1[4] = {0.f, 0.f, 0.f, 0.f};
    float acc2[4] = {0.f, 0.f, 0.f, 0.f};
    float den1 = 0.f, den2 = 0.f;

    // prefix contribution: q broadcast over cluster via width-8 shfl
    #pragma unroll
    for (int who = 0; who < 8; ++who) {
        #pragma unroll
        for (int i = 0; i < 4; ++i) {
            const int e = who * 4 + i;
            const float q1 = __shfl(q1r[i], who, 8);
            const float q2 = __shfl(q2r[i], who, 8);
            den1 += q1 * k1p[e];
            den2 += q2 * k2p[e];
            const float4 sa = *(const float4*)&S1p[e * EE + d0];
            const float4 ta = *(const float4*)&S2p[e * EE + d0];
            acc1[0] += q1 * sa.x; acc1[1] += q1 * sa.y;
            acc1[2] += q1 * sa.z; acc1[3] += q1 * sa.w;
            acc2[0] += q2 * ta.x; acc2[1] += q2 * ta.y;
            acc2[2] += q2 * ta.z; acc2[3] += q2 * ta.w;
        }
    }

    // intra-chunk causal: cluster dot + width-8 reduce
    for (int j = 0; j <= r; ++j) {
        const float4 ka = *(const float4*)&K1n[j][d0];
        const float4 la = *(const float4*)&K2n[j][d0];
        float p1 = q1r[0]*ka.x + q1r[1]*ka.y + q1r[2]*ka.z + q1r[3]*ka.w;
        float p2 = q2r[0]*la.x + q2r[1]*la.y + q2r[2]*la.z + q2r[3]*la.w;
        p1 += __shfl_xor(p1, 1, 8); p1 += __shfl_xor(p1, 2, 8); p1 += __shfl_xor(p1, 4, 8);
        p2 += __shfl_xor(p2, 1, 8); p2 += __shfl_xor(p2, 2, 8); p2 += __shfl_xor(p2, 4, 8);
        den1 += p1;
        den2 += p2;
        const float4 va = *(const float4*)&Vs[9 + j][d0];
        acc1[0] += p1 * va.x; acc1[1] += p1 * va.y;
        acc1[2] += p1 * va.z; acc1[3] += p1 * va.w;
        acc2[0] += p2 * va.x; acc2[1] += p2 * va.y;
        acc2[2] += p2 * va.z; acc2[3] += p2 * va.w;
    }

    const float z1 = 1.f / (den1 + EPSF);
    const float z2 = 1.f / (den2 + EPSF);
    const float4 w2 = *(const float4*)&W2[h * EE + d0];
    const float4 w3 = *(const float4*)&W3[h * EE + d0];
    float4 o;
    o.x = bnd[0] + w2.x * acc1[0] * z1 + w3.x * acc2[0] * z2;
    o.y = bnd[1] + w2.y * acc1[1] * z1 + w3.y * acc2[1] * z2;
    o.z = bnd[2] + w2.z * acc1[2] * z1 + w3.z * acc2[2] * z2;
    o.w = bnd[3] + w2.w * acc1[3] * z1 + w3.w * acc2[3] * z2;
    *(float4*)&out[((n * LL + l) * HH + h) * EE + d0] = o;
}

extern "C" void kernel_launch(void* const* d_in, const int* in_sizes, int n_in,
                              void* d_out, int out_size, void* d_ws, size_t ws_size,
                              hipStream_t stream)
{
    const float* Q  = (const float*)d_in[0];
    const float* K  = (const float*)d_in[1];
    const float* V  = (const float*)d_in[2];
    const float* KL = (const float*)d_in[3];
    const float* W1 = (const float*)d_in[4];
    const float* W2 = (const float*)d_in[5];
    const float* W3 = (const float*)d_in[6];
    float* out = (float*)d_out;
    float* ws  = (float*)d_ws;   // uses NB*REC*4 = ~4.3 MB of scratch

    chunksum_kernel<<<NB,           512, 0, stream>>>(K, V, KL, ws);
    prefix_kernel  <<<NN * HH * 11, 192, 0, stream>>>(ws);
    fused_kernel   <<<NB,           512, 0, stream>>>(Q, K, V, KL, W1, W2, W3, ws, out);
}